// Round 6
// baseline (226.448 us; speedup 1.0000x reference)
//
#include <hip/hip_runtime.h>

#define N_NODES 100000
#define N_EDGES 1600000
#define D 64
#define N_BBOX 4096
#define CAP 64  // per-node slot capacity; deg ~ Poisson(16), P(>=64) ~ 1e-20
#define NBITW 3136  // words for N_NODES bits, padded

__device__ __forceinline__ float readlane_f(float v, int l) {
  return __int_as_float(__builtin_amdgcn_readlane(__float_as_int(v), l));
}
__device__ __forceinline__ int bperm(int srclane, int v) {
  return __builtin_amdgcn_ds_bpermute(srclane << 2, v);
}
__device__ __forceinline__ float lrelu(float v) {
  return fmaxf(v, 0.01f * v);  // neg_slope 0.01 > 0
}
__device__ __forceinline__ bool testbit(const unsigned* bits, int i) {
  return (bits[i >> 5] >> (i & 31)) & 1u;
}

// ---- mark bbox nodes in both bitmasks (12.5 KB each -> L1-resident) ----
__global__ __launch_bounds__(256) void mark_kernel(const int* __restrict__ bbox,
                                                   unsigned* __restrict__ is_bbox_bits,
                                                   unsigned* __restrict__ needed_bits) {
  int t = blockIdx.x * blockDim.x + threadIdx.x;
  if (t < N_BBOX) {
    int n = bbox[t];
    unsigned m = 1u << (n & 31);
    atomicOr(&is_bbox_bits[n >> 5], m);
    atomicOr(&needed_bits[n >> 5], m);
  }
}

// ---- mark srcs of edges landing on bbox nodes (dst-first; src only on hit) ----
__global__ __launch_bounds__(256) void mark_needed_kernel(
    const int* __restrict__ src, const int* __restrict__ dst,
    const unsigned* __restrict__ is_bbox_bits, unsigned* __restrict__ needed_bits) {
  int e = blockIdx.x * blockDim.x + threadIdx.x;
  if (e >= N_EDGES) return;
  int d = dst[e];
  if (testbit(is_bbox_bits, d)) {  // ~4% of lanes; is_bbox_bits is L1-hit
    int s = src[e];
    atomicOr(&needed_bits[s >> 5], 1u << (s & 31));
  }
}

// ---- per-node slot fill, filtered to needed dst (~50% of edges) ----
__global__ __launch_bounds__(256) void fill_kernel(const int* __restrict__ src,
                                                   const int* __restrict__ dst,
                                                   const unsigned* __restrict__ needed_bits,
                                                   int* __restrict__ cnt,
                                                   int* __restrict__ slots) {
  int e = blockIdx.x * blockDim.x + threadIdx.x;
  if (e >= N_EDGES) return;
  int d = dst[e];
  if (!testbit(needed_bits, d)) return;  // L1-hit filter
  int p = atomicAdd(&cnt[d], 1);
  if (p < CAP) slots[(size_t)d * CAP + p] = src[e];
}

// ---- layer-1 fused gather+dense over needed nodes ----
// Gather: 4 edges/float4-instr, 16 edges in flight. After the xor-shfl
// reduction every lane holds the replicated agg row (a_{4c+u} = comp u of
// lane c), so the dense runs immediately in-register; h1 written directly.
__global__ __launch_bounds__(256, 1) void layer1_fused_kernel(
    const float4* __restrict__ x4, const unsigned* __restrict__ needed_bits,
    const int* __restrict__ cnt, const int* __restrict__ slots,
    const float* __restrict__ W1rel, const float* __restrict__ b1,
    const float* __restrict__ W1root, float* __restrict__ hbuf) {
  const int lane = threadIdx.x & 63;
  const int wid0 = (blockIdx.x * blockDim.x + threadIdx.x) >> 6;
  const int nw = (gridDim.x * blockDim.x) >> 6;
  const int g = lane >> 4, c = lane & 15;

  float wrel[D], wroot[D];
#pragma unroll
  for (int k = 0; k < D; k++) {
    wrel[k] = W1rel[k * D + lane];
    wroot[k] = W1root[k * D + lane];
  }
  const float bj = b1[lane];

  for (int i = wid0; i < N_NODES; i += nw) {
    if (!testbit(needed_bits, i)) continue;  // wave-uniform scalar test
    int n = cnt[i];
    n = (n > CAP) ? CAP : n;
    const int myslot = (lane < n) ? slots[(size_t)i * CAP + lane] : 0;

    float4 acc = make_float4(0.f, 0.f, 0.f, 0.f);
    for (int e0 = 0; e0 < n; e0 += 16) {
      int idx[4], s[4];
      float4 v[4];
#pragma unroll
      for (int u = 0; u < 4; u++) {
        idx[u] = e0 + u * 4 + g;
        s[u] = bperm(idx[u], myslot);
      }
#pragma unroll
      for (int u = 0; u < 4; u++) {
        v[u] = make_float4(0.f, 0.f, 0.f, 0.f);
        if (idx[u] < n) v[u] = x4[(size_t)s[u] * 16 + c];
      }
#pragma unroll
      for (int u = 0; u < 4; u++) {
        acc.x += v[u].x; acc.y += v[u].y; acc.z += v[u].z; acc.w += v[u].w;
      }
    }
    acc.x += __shfl_xor(acc.x, 16); acc.y += __shfl_xor(acc.y, 16);
    acc.z += __shfl_xor(acc.z, 16); acc.w += __shfl_xor(acc.w, 16);
    acc.x += __shfl_xor(acc.x, 32); acc.y += __shfl_xor(acc.y, 32);
    acc.z += __shfl_xor(acc.z, 32); acc.w += __shfl_xor(acc.w, 32);

    const float xi = ((const float*)x4)[(size_t)i * D + lane];
    float s0 = 0.f, s1 = 0.f, s2 = 0.f, s3 = 0.f;
#pragma unroll
    for (int k = 0; k < D; k += 2) {
      const float a0 = (k & 2) ? readlane_f(acc.z, k >> 2) : readlane_f(acc.x, k >> 2);
      const float a1 = ((k + 1) & 2) ? readlane_f(acc.w, (k + 1) >> 2)
                                     : readlane_f(acc.y, (k + 1) >> 2);
      s0 += a0 * wrel[k];
      s1 += readlane_f(xi, k) * wroot[k];
      s2 += a1 * wrel[k + 1];
      s3 += readlane_f(xi, k + 1) * wroot[k + 1];
    }
    hbuf[(size_t)i * D + lane] = lrelu(bj + ((s0 + s1) + (s2 + s3)));
  }
}

// ---- layer-2: fused gather + dense, bbox rows only ----
__global__ __launch_bounds__(256, 1) void layer2_kernel(
    const float4* __restrict__ h4, const int* __restrict__ cnt,
    const int* __restrict__ slots, const int* __restrict__ bbox,
    const float* __restrict__ W2rel, const float* __restrict__ b2,
    const float* __restrict__ W2root, float* __restrict__ out) {
  const int t = (blockIdx.x * blockDim.x + threadIdx.x) >> 6;
  if (t >= N_BBOX) return;
  const int lane = threadIdx.x & 63;
  const int g = lane >> 4, c = lane & 15;

  float wrel[D], wroot[D];
#pragma unroll
  for (int k = 0; k < D; k++) {
    wrel[k] = W2rel[k * D + lane];
    wroot[k] = W2root[k * D + lane];
  }
  const float bj = b2[lane];

  const int node = __builtin_amdgcn_readfirstlane(bbox[t]);
  int n = cnt[node];
  n = (n > CAP) ? CAP : n;
  const int myslot = (lane < n) ? slots[(size_t)node * CAP + lane] : 0;

  float4 acc = make_float4(0.f, 0.f, 0.f, 0.f);
  for (int e0 = 0; e0 < n; e0 += 32) {
    int idx[8], s[8];
    float4 v[8];
#pragma unroll
    for (int u = 0; u < 8; u++) {
      idx[u] = e0 + u * 4 + g;
      s[u] = bperm(idx[u], myslot);
    }
#pragma unroll
    for (int u = 0; u < 8; u++) {
      v[u] = make_float4(0.f, 0.f, 0.f, 0.f);
      if (idx[u] < n) v[u] = h4[(size_t)s[u] * 16 + c];
    }
#pragma unroll
    for (int u = 0; u < 8; u++) {
      acc.x += v[u].x; acc.y += v[u].y; acc.z += v[u].z; acc.w += v[u].w;
    }
  }
  acc.x += __shfl_xor(acc.x, 16); acc.y += __shfl_xor(acc.y, 16);
  acc.z += __shfl_xor(acc.z, 16); acc.w += __shfl_xor(acc.w, 16);
  acc.x += __shfl_xor(acc.x, 32); acc.y += __shfl_xor(acc.y, 32);
  acc.z += __shfl_xor(acc.z, 32); acc.w += __shfl_xor(acc.w, 32);

  const float hi = ((const float*)h4)[(size_t)node * D + lane];
  float s0 = 0.f, s1 = 0.f, s2 = 0.f, s3 = 0.f;
#pragma unroll
  for (int k = 0; k < D; k += 2) {
    const float a0 = (k & 2) ? readlane_f(acc.z, k >> 2) : readlane_f(acc.x, k >> 2);
    const float a1 = ((k + 1) & 2) ? readlane_f(acc.w, (k + 1) >> 2)
                                   : readlane_f(acc.y, (k + 1) >> 2);
    s0 += a0 * wrel[k];
    s1 += readlane_f(hi, k) * wroot[k];
    s2 += a1 * wrel[k + 1];
    s3 += readlane_f(hi, k + 1) * wroot[k + 1];
  }
  out[(size_t)t * D + lane] = lrelu(bj + ((s0 + s1) + (s2 + s3)));
}

// ---------------- launch ----------------

extern "C" void kernel_launch(void* const* d_in, const int* in_sizes, int n_in,
                              void* d_out, int out_size, void* d_ws, size_t ws_size,
                              hipStream_t stream) {
  const float* x = (const float*)d_in[0];
  const int* ei = (const int*)d_in[1];
  const int* src = ei;
  const int* dst = ei + N_EDGES;
  const int* bbox = (const int*)d_in[2];
  const float* W1rel = (const float*)d_in[3];
  const float* b1 = (const float*)d_in[4];
  const float* W1root = (const float*)d_in[5];
  const float* W2rel = (const float*)d_in[6];
  const float* b2 = (const float*)d_in[7];
  const float* W2root = (const float*)d_in[8];
  float* out = (float*)d_out;

  char* ws = (char*)d_ws;
  size_t off = 0;
  auto alloc = [&](size_t bytes) -> char* {
    char* p = ws + off;
    off = (off + bytes + 511) & ~(size_t)511;
    return p;
  };
  // contiguous zero region: bitmasks + cnt (~425 KB, one memset)
  unsigned* is_bbox_bits = (unsigned*)alloc(NBITW * sizeof(unsigned));
  unsigned* needed_bits = (unsigned*)alloc(NBITW * sizeof(unsigned));
  int* cnt = (int*)alloc(N_NODES * sizeof(int));
  char* zero_end = ws + off;
  int* slots = (int*)alloc((size_t)N_NODES * CAP * sizeof(int));    // 25.6 MB
  float* hbuf = (float*)alloc((size_t)N_NODES * D * sizeof(float)); // 25.6 MB

  hipMemsetAsync(is_bbox_bits, 0, (size_t)(zero_end - (char*)is_bbox_bits), stream);
  mark_kernel<<<(N_BBOX + 255) / 256, 256, 0, stream>>>(bbox, is_bbox_bits,
                                                        needed_bits);
  mark_needed_kernel<<<(N_EDGES + 255) / 256, 256, 0, stream>>>(
      src, dst, is_bbox_bits, needed_bits);
  fill_kernel<<<(N_EDGES + 255) / 256, 256, 0, stream>>>(src, dst, needed_bits,
                                                         cnt, slots);
  layer1_fused_kernel<<<2048, 256, 0, stream>>>(
      (const float4*)x, needed_bits, cnt, slots, W1rel, b1, W1root, hbuf);
  layer2_kernel<<<(N_BBOX + 3) / 4, 256, 0, stream>>>(
      (const float4*)hbuf, cnt, slots, bbox, W2rel, b2, W2root, out);
}

// Round 7
// 201.678 us; speedup vs baseline: 1.1228x; 1.1228x over previous
//
#include <hip/hip_runtime.h>

#define N_NODES 100000
#define N_EDGES 1600000
#define D 64
#define N_BBOX 4096
#define CAP 64      // per-node slot capacity; deg ~ Poisson(16), P(>=64) ~ 1e-20
#define NBITW 3136  // words for N_NODES bits, padded

typedef short bf16x8 __attribute__((ext_vector_type(8)));
typedef float f32x4 __attribute__((ext_vector_type(4)));

__device__ __forceinline__ float readlane_f(float v, int l) {
  return __int_as_float(__builtin_amdgcn_readlane(__float_as_int(v), l));
}
__device__ __forceinline__ int bperm(int srclane, int v) {
  return __builtin_amdgcn_ds_bpermute(srclane << 2, v);
}
__device__ __forceinline__ float lrelu(float v) {
  return fmaxf(v, 0.01f * v);  // neg_slope 0.01 > 0
}
__device__ __forceinline__ bool testbit(const unsigned* bits, int i) {
  return (bits[i >> 5] >> (i & 31)) & 1u;
}
__device__ __forceinline__ short f2bf(float f) {  // RNE fp32 -> bf16
  unsigned u = __float_as_uint(f);
  u += 0x7FFFu + ((u >> 16) & 1u);
  return (short)(u >> 16);
}
__device__ __forceinline__ bf16x8 pack_bf8(float4 lo, float4 hi) {
  bf16x8 r;
  r[0] = f2bf(lo.x); r[1] = f2bf(lo.y); r[2] = f2bf(lo.z); r[3] = f2bf(lo.w);
  r[4] = f2bf(hi.x); r[5] = f2bf(hi.y); r[6] = f2bf(hi.z); r[7] = f2bf(hi.w);
  return r;
}

// ---- mark bbox nodes in both bitmasks (12.5 KB each -> L1-resident) ----
__global__ __launch_bounds__(256) void mark_kernel(const int* __restrict__ bbox,
                                                   unsigned* __restrict__ is_bbox_bits,
                                                   unsigned* __restrict__ needed_bits) {
  int t = blockIdx.x * blockDim.x + threadIdx.x;
  if (t < N_BBOX) {
    int n = bbox[t];
    unsigned m = 1u << (n & 31);
    atomicOr(&is_bbox_bits[n >> 5], m);
    atomicOr(&needed_bits[n >> 5], m);
  }
}

// ---- mark srcs of edges landing on bbox nodes ----
__global__ __launch_bounds__(256) void mark_needed_kernel(
    const int* __restrict__ src, const int* __restrict__ dst,
    const unsigned* __restrict__ is_bbox_bits, unsigned* __restrict__ needed_bits) {
  int e = blockIdx.x * blockDim.x + threadIdx.x;
  if (e >= N_EDGES) return;
  int d = dst[e];
  if (testbit(is_bbox_bits, d)) {  // ~4% of lanes; L1-hit filter
    int s = src[e];
    atomicOr(&needed_bits[s >> 5], 1u << (s & 31));
  }
}

// ---- per-node slot fill, filtered to needed dst (~50% of edges) ----
__global__ __launch_bounds__(256) void fill_kernel(const int* __restrict__ src,
                                                   const int* __restrict__ dst,
                                                   const unsigned* __restrict__ needed_bits,
                                                   int* __restrict__ cnt,
                                                   int* __restrict__ slots) {
  int e = blockIdx.x * blockDim.x + threadIdx.x;
  if (e >= N_EDGES) return;
  int d = dst[e];
  if (!testbit(needed_bits, d)) return;
  int p = atomicAdd(&cnt[d], 1);
  if (p < CAP) slots[(size_t)d * CAP + p] = src[e];
}

// ---- layer-1 gather (needed nodes only): 4 edges/instr, 32 in flight ----
__global__ __launch_bounds__(256) void gather1_kernel(const float4* __restrict__ x4,
                                                      const unsigned* __restrict__ needed_bits,
                                                      const int* __restrict__ cnt,
                                                      const int* __restrict__ slots,
                                                      float4* __restrict__ agg4) {
  const int wid = (blockIdx.x * blockDim.x + threadIdx.x) >> 6;
  if (wid >= N_NODES) return;
  if (!testbit(needed_bits, wid)) return;
  const int lane = threadIdx.x & 63;
  const int g = lane >> 4, c = lane & 15;

  int n = cnt[wid];
  n = (n > CAP) ? CAP : n;
  const int myslot = (lane < n) ? slots[(size_t)wid * CAP + lane] : 0;

  float4 acc = make_float4(0.f, 0.f, 0.f, 0.f);
  for (int e0 = 0; e0 < n; e0 += 32) {
    int idx[8], s[8];
    float4 v[8];
#pragma unroll
    for (int u = 0; u < 8; u++) {
      idx[u] = e0 + u * 4 + g;
      s[u] = bperm(idx[u], myslot);
    }
#pragma unroll
    for (int u = 0; u < 8; u++) {
      v[u] = make_float4(0.f, 0.f, 0.f, 0.f);
      if (idx[u] < n) v[u] = x4[(size_t)s[u] * 16 + c];
    }
#pragma unroll
    for (int u = 0; u < 8; u++) {
      acc.x += v[u].x; acc.y += v[u].y; acc.z += v[u].z; acc.w += v[u].w;
    }
  }
  acc.x += __shfl_xor(acc.x, 16); acc.y += __shfl_xor(acc.y, 16);
  acc.z += __shfl_xor(acc.z, 16); acc.w += __shfl_xor(acc.w, 16);
  acc.x += __shfl_xor(acc.x, 32); acc.y += __shfl_xor(acc.y, 32);
  acc.z += __shfl_xor(acc.z, 32); acc.w += __shfl_xor(acc.w, 32);
  if (g == 0) agg4[(size_t)wid * 16 + c] = acc;
}

// ---- layer-1 dense via MFMA: h = lrelu(agg@W1rel + b1 + x@W1root), in place ----
// One wave per 16-node tile (grid-stride). mfma_f32_16x16x32_bf16 layouts
// (HW-verified): A[m=lane&15][k=quad*8+i], B[k=quad*8+i][n=lane&15],
// C col=lane&15, row=quad*4+reg. W held as B-fragments (64 VGPRs), loaded once.
// Runs over ALL tiles (needed-density ~50% => tile-skip never fires; poison
// agg rows are finite floats, row-independent in MFMA, never read again).
__global__ __launch_bounds__(256, 1) void dense1_mfma_kernel(
    const float* __restrict__ x, const float* __restrict__ W1rel,
    const float* __restrict__ b1, const float* __restrict__ W1root,
    float* __restrict__ hbuf) {
  const int lane = threadIdx.x & 63;
  const int cn = lane & 15;    // A-row m / B-col n / C-col
  const int quad = lane >> 4;  // k-block selector / C row-block
  const int wid0 = (blockIdx.x * blockDim.x + threadIdx.x) >> 6;
  const int nwaves = (gridDim.x * blockDim.x) >> 6;

  bf16x8 brel[2][4], broot[2][4];
#pragma unroll
  for (int kh = 0; kh < 2; kh++)
#pragma unroll
    for (int nt = 0; nt < 4; nt++)
#pragma unroll
      for (int i = 0; i < 8; i++) {
        const int k = kh * 32 + quad * 8 + i;
        brel[kh][nt][i] = f2bf(W1rel[k * D + nt * 16 + cn]);
        broot[kh][nt][i] = f2bf(W1root[k * D + nt * 16 + cn]);
      }
  float bj[4];
#pragma unroll
  for (int nt = 0; nt < 4; nt++) bj[nt] = b1[nt * 16 + cn];

  for (int tile = wid0; tile < N_NODES / 16; tile += nwaves) {
    const int node0 = tile * 16;
    const float* arow = hbuf + (size_t)(node0 + cn) * D;
    const float* xrow = x + (size_t)(node0 + cn) * D;

    f32x4 acc[4] = {};
#pragma unroll
    for (int kh = 0; kh < 2; kh++) {
      const int kb = kh * 32 + quad * 8;
      const float4 fa0 = *(const float4*)(arow + kb);
      const float4 fa1 = *(const float4*)(arow + kb + 4);
      const float4 fx0 = *(const float4*)(xrow + kb);
      const float4 fx1 = *(const float4*)(xrow + kb + 4);
      const bf16x8 a_agg = pack_bf8(fa0, fa1);
      const bf16x8 a_x = pack_bf8(fx0, fx1);
#pragma unroll
      for (int nt = 0; nt < 4; nt++) {
        acc[nt] = __builtin_amdgcn_mfma_f32_16x16x32_bf16(a_agg, brel[kh][nt],
                                                          acc[nt], 0, 0, 0);
        acc[nt] = __builtin_amdgcn_mfma_f32_16x16x32_bf16(a_x, broot[kh][nt],
                                                          acc[nt], 0, 0, 0);
      }
    }
#pragma unroll
    for (int nt = 0; nt < 4; nt++) {
#pragma unroll
      for (int r = 0; r < 4; r++) {
        const int row = quad * 4 + r;
        hbuf[(size_t)(node0 + row) * D + nt * 16 + cn] = lrelu(acc[nt][r] + bj[nt]);
      }
    }
  }
}

// ---- layer-2: fused gather + dense, bbox rows only (fp32) ----
__global__ __launch_bounds__(256, 1) void layer2_kernel(
    const float4* __restrict__ h4, const int* __restrict__ cnt,
    const int* __restrict__ slots, const int* __restrict__ bbox,
    const float* __restrict__ W2rel, const float* __restrict__ b2,
    const float* __restrict__ W2root, float* __restrict__ out) {
  const int t = (blockIdx.x * blockDim.x + threadIdx.x) >> 6;
  if (t >= N_BBOX) return;
  const int lane = threadIdx.x & 63;
  const int g = lane >> 4, c = lane & 15;

  float wrel[D], wroot[D];
#pragma unroll
  for (int k = 0; k < D; k++) {
    wrel[k] = W2rel[k * D + lane];
    wroot[k] = W2root[k * D + lane];
  }
  const float bj = b2[lane];

  const int node = __builtin_amdgcn_readfirstlane(bbox[t]);
  int n = cnt[node];
  n = (n > CAP) ? CAP : n;
  const int myslot = (lane < n) ? slots[(size_t)node * CAP + lane] : 0;

  float4 acc = make_float4(0.f, 0.f, 0.f, 0.f);
  for (int e0 = 0; e0 < n; e0 += 32) {
    int idx[8], s[8];
    float4 v[8];
#pragma unroll
    for (int u = 0; u < 8; u++) {
      idx[u] = e0 + u * 4 + g;
      s[u] = bperm(idx[u], myslot);
    }
#pragma unroll
    for (int u = 0; u < 8; u++) {
      v[u] = make_float4(0.f, 0.f, 0.f, 0.f);
      if (idx[u] < n) v[u] = h4[(size_t)s[u] * 16 + c];
    }
#pragma unroll
    for (int u = 0; u < 8; u++) {
      acc.x += v[u].x; acc.y += v[u].y; acc.z += v[u].z; acc.w += v[u].w;
    }
  }
  acc.x += __shfl_xor(acc.x, 16); acc.y += __shfl_xor(acc.y, 16);
  acc.z += __shfl_xor(acc.z, 16); acc.w += __shfl_xor(acc.w, 16);
  acc.x += __shfl_xor(acc.x, 32); acc.y += __shfl_xor(acc.y, 32);
  acc.z += __shfl_xor(acc.z, 32); acc.w += __shfl_xor(acc.w, 32);

  const float hi = ((const float*)h4)[(size_t)node * D + lane];
  float s0 = 0.f, s1 = 0.f, s2 = 0.f, s3 = 0.f;
#pragma unroll
  for (int k = 0; k < D; k += 2) {
    const float a0 = (k & 2) ? readlane_f(acc.z, k >> 2) : readlane_f(acc.x, k >> 2);
    const float a1 = ((k + 1) & 2) ? readlane_f(acc.w, (k + 1) >> 2)
                                   : readlane_f(acc.y, (k + 1) >> 2);
    s0 += a0 * wrel[k];
    s1 += readlane_f(hi, k) * wroot[k];
    s2 += a1 * wrel[k + 1];
    s3 += readlane_f(hi, k + 1) * wroot[k + 1];
  }
  out[(size_t)t * D + lane] = lrelu(bj + ((s0 + s1) + (s2 + s3)));
}

// ---------------- launch ----------------

extern "C" void kernel_launch(void* const* d_in, const int* in_sizes, int n_in,
                              void* d_out, int out_size, void* d_ws, size_t ws_size,
                              hipStream_t stream) {
  const float* x = (const float*)d_in[0];
  const int* ei = (const int*)d_in[1];
  const int* src = ei;
  const int* dst = ei + N_EDGES;
  const int* bbox = (const int*)d_in[2];
  const float* W1rel = (const float*)d_in[3];
  const float* b1 = (const float*)d_in[4];
  const float* W1root = (const float*)d_in[5];
  const float* W2rel = (const float*)d_in[6];
  const float* b2 = (const float*)d_in[7];
  const float* W2root = (const float*)d_in[8];
  float* out = (float*)d_out;

  char* ws = (char*)d_ws;
  size_t off = 0;
  auto alloc = [&](size_t bytes) -> char* {
    char* p = ws + off;
    off = (off + bytes + 511) & ~(size_t)511;
    return p;
  };
  // contiguous zero region: bitmasks + cnt (~425 KB, one memset)
  unsigned* is_bbox_bits = (unsigned*)alloc(NBITW * sizeof(unsigned));
  unsigned* needed_bits = (unsigned*)alloc(NBITW * sizeof(unsigned));
  int* cnt = (int*)alloc(N_NODES * sizeof(int));
  char* zero_end = ws + off;
  int* slots = (int*)alloc((size_t)N_NODES * CAP * sizeof(int));    // 25.6 MB
  float* hbuf = (float*)alloc((size_t)N_NODES * D * sizeof(float)); // 25.6 MB

  hipMemsetAsync(is_bbox_bits, 0, (size_t)(zero_end - (char*)is_bbox_bits), stream);
  mark_kernel<<<(N_BBOX + 255) / 256, 256, 0, stream>>>(bbox, is_bbox_bits,
                                                        needed_bits);
  mark_needed_kernel<<<(N_EDGES + 255) / 256, 256, 0, stream>>>(
      src, dst, is_bbox_bits, needed_bits);
  fill_kernel<<<(N_EDGES + 255) / 256, 256, 0, stream>>>(src, dst, needed_bits,
                                                         cnt, slots);
  gather1_kernel<<<(N_NODES + 3) / 4, 256, 0, stream>>>(
      (const float4*)x, needed_bits, cnt, slots, (float4*)hbuf);
  dense1_mfma_kernel<<<512, 256, 0, stream>>>(x, W1rel, b1, W1root, hbuf);
  layer2_kernel<<<(N_BBOX + 3) / 4, 256, 0, stream>>>(
      (const float4*)hbuf, cnt, slots, bbox, W2rel, b2, W2root, out);
}